// Round 11
// baseline (11174.126 us; speedup 1.0000x reference)
//
#include <hip/hip_runtime.h>
#include <hip/hip_bf16.h>
#include <stdint.h>

#define KKTOT 100000
#define BAP   2048
#define KPADMAX 100352   // 49*2048

typedef _Float16 f16x8 __attribute__((ext_vector_type(8)));
typedef float    f32x4 __attribute__((ext_vector_type(4)));

// ---- constants (match reference f32 arithmetic) ----
__device__ __constant__ float KCf  = (float)(4.0 * 3.14159265358979323846 * 77.0e9 / 299792458.0);
__device__ __constant__ float I2PA = (float)(0.15915494309189534940823);
__device__ __constant__ float I2PB = (float)(0.15915494309189534940823 - (double)(float)(0.15915494309189534940823));

__device__ __forceinline__ float phase_frac(float dy, float dxx) {
    float d2 = fmaf(dy, dy, fmaf(dxx, dxx, 0.09f));
    float ph = KCf * sqrtf(d2);
    float h  = ph * I2PA;
    float l  = fmaf(ph, I2PA, -h);
    l = fmaf(ph, I2PB, l);
    return (h - floorf(h)) + l;                  // revolutions
}

__device__ __forceinline__ void gload16(const void* g, void* l) {
    __builtin_amdgcn_global_load_lds(
        (__attribute__((address_space(1))) void*)(uintptr_t)g,
        (__attribute__((address_space(3))) void*)(uint32_t)(uintptr_t)l,
        16, 0, 0);
}

__device__ __forceinline__ float2 cmulf(float2 a, float2 b) {
    return make_float2(a.x*b.x - a.y*b.y, a.x*b.y + a.y*b.x);
}

// ---------------- decode py (int32) ----------------
__global__ __launch_bounds__(256) void decode_k(const float* __restrict__ sar, const int* __restrict__ py,
                                                float* __restrict__ ay, float* __restrict__ ax, float* __restrict__ rd) {
    int i = blockIdx.x * 256 + threadIdx.x;
    if (i >= KKTOT) return;
    int p = py[i];
    int iy = p & 511, ix = p >> 9;
    ay[i] = ((float)iy + 0.5f - 256.0f) * 1e-3f;
    ax[i] = ((float)ix + 0.5f - 256.0f) * 1e-3f;
    rd[i] = sar[p];
}

// ---------------- generate C=cos, S=sin as f16, layout [2048][Kc] ----------------
__global__ __launch_bounds__(256) void gen_cs(_Float16* __restrict__ C, _Float16* __restrict__ S,
                                              const float* __restrict__ ay, const float* __restrict__ ax,
                                              int k0, int Kc) {
    int j = blockIdx.y;
    long long kk = ((long long)blockIdx.x * 256 + threadIdx.x) * 8;
    size_t o = (size_t)j * Kc + kk;
    long long kg = (long long)k0 + kk;
    f16x8 cv, sv;
    if (j < 2000 && kg < KKTOT) {
        int jy = j % 40, jx = j / 40;
        float why = ((float)jy * (200.0f/39.0f) - 100.0f) * 1e-3f;   // wh2[jy]
        float whx = ((float)jx * (200.0f/49.0f) - 100.0f) * 1e-3f;   // wh1[jx]
        float4 a0 = *(const float4*)(ay + kg);
        float4 a1 = *(const float4*)(ay + kg + 4);
        float4 b0 = *(const float4*)(ax + kg);
        float4 b1 = *(const float4*)(ax + kg + 4);
        float ayv[8] = {a0.x,a0.y,a0.z,a0.w,a1.x,a1.y,a1.z,a1.w};
        float axv[8] = {b0.x,b0.y,b0.z,b0.w,b1.x,b1.y,b1.z,b1.w};
        #pragma unroll
        for (int e = 0; e < 8; ++e) {
            float fr = phase_frac(ayv[e]-why, axv[e]-whx);
            cv[e] = (_Float16)__builtin_amdgcn_cosf(fr);
            sv[e] = (_Float16)__builtin_amdgcn_sinf(fr);
        }
    } else {
        #pragma unroll
        for (int e = 0; e < 8; ++e) { cv[e] = (_Float16)0.f; sv[e] = (_Float16)0.f; }
    }
    *(f16x8*)(C + o) = cv;
    *(f16x8*)(S + o) = sv;
}

// ---------------- UPPER-TRIANGLE fused Gram GEMM (compact grid, z=8, atomic epilogue) ----------------
__global__ __launch_bounds__(256) void gemm_ut(const _Float16* __restrict__ C, const _Float16* __restrict__ S,
                                               float* __restrict__ R, float* __restrict__ Pm,
                                               int kiters, int kstride) {
    int rem = blockIdx.x;
    int mi = 0;
    #pragma unroll
    for (int r = 0; r < 16; ++r) {
        int cnt = 16 - r;
        if (rem < cnt) { mi = r; break; }
        rem -= cnt;
    }
    const int ni = mi + rem;
    const int z = blockIdx.y;

    __shared__ _Float16 ldsCa[8192];
    __shared__ _Float16 ldsSa[8192];
    __shared__ _Float16 ldsCb[8192];
    __shared__ _Float16 ldsSb[8192];
    const int t = threadIdx.x;
    const int w = t >> 6;
    const int lane = t & 63;

    f32x4 accR[4][4], accP[4][4];
    #pragma unroll
    for (int a = 0; a < 4; ++a)
        #pragma unroll
        for (int b = 0; b < 4; ++b) { accR[a][b] = (f32x4){0.f,0.f,0.f,0.f}; accP[a][b] = (f32x4){0.f,0.f,0.f,0.f}; }

    size_t aoff[4], boff[4];
    #pragma unroll
    for (int r = 0; r < 4; ++r) {
        int c = r * 256 + t;
        int jl = c >> 3;
        int ks = (c & 7) ^ (jl & 7);
        aoff[r] = (size_t)(mi*128 + jl) * kstride + ks*8;
        boff[r] = (size_t)(ni*128 + jl) * kstride + ks*8;
    }
    const int wm = w & 1, wn = w >> 1;
    const int q = lane >> 4, lm = lane & 15;
    const int ajl = wm*64 + lm;
    const int aoffl = (ajl*8 + (q ^ (ajl & 7))) * 16;
    const int bjl = wn*64 + lm;
    const int boffl = (bjl*8 + (q ^ (bjl & 7))) * 16;

    const int kq = kiters >> 3;
    for (int kt = z*kq; kt < (z+1)*kq; ++kt) {
        __syncthreads();
        const _Float16* gc = C + (size_t)kt * 64;
        const _Float16* gs = S + (size_t)kt * 64;
        #pragma unroll
        for (int r = 0; r < 4; ++r) {
            size_t dst = (size_t)(r*256 + w*64)*16;
            gload16(gc + aoff[r], (char*)ldsCa + dst);
            gload16(gs + aoff[r], (char*)ldsSa + dst);
            gload16(gc + boff[r], (char*)ldsCb + dst);
            gload16(gs + boff[r], (char*)ldsSb + dst);
        }
        __syncthreads();
        #pragma unroll
        for (int ks = 0; ks < 2; ++ks) {
            f16x8 bfC[4], bfS[4];
            #pragma unroll
            for (int nt = 0; nt < 4; ++nt) {
                bfC[nt] = *(const f16x8*)((const char*)ldsCb + ((boffl ^ (ks*64)) + nt*2048));
                bfS[nt] = *(const f16x8*)((const char*)ldsSb + ((boffl ^ (ks*64)) + nt*2048));
            }
            #pragma unroll
            for (int mt = 0; mt < 4; ++mt) {
                f16x8 afC = *(const f16x8*)((const char*)ldsCa + ((aoffl ^ (ks*64)) + mt*2048));
                f16x8 afS = *(const f16x8*)((const char*)ldsSa + ((aoffl ^ (ks*64)) + mt*2048));
                f16x8 nfS;
                #pragma unroll
                for (int e = 0; e < 8; ++e) nfS[e] = -afS[e];
                #pragma unroll
                for (int nt = 0; nt < 4; ++nt) {
                    accR[mt][nt] = __builtin_amdgcn_mfma_f32_16x16x32_f16(afC, bfC[nt], accR[mt][nt], 0, 0, 0);
                    accR[mt][nt] = __builtin_amdgcn_mfma_f32_16x16x32_f16(afS, bfS[nt], accR[mt][nt], 0, 0, 0);
                    accP[mt][nt] = __builtin_amdgcn_mfma_f32_16x16x32_f16(afC, bfS[nt], accP[mt][nt], 0, 0, 0);
                    accP[mt][nt] = __builtin_amdgcn_mfma_f32_16x16x32_f16(nfS, bfC[nt], accP[mt][nt], 0, 0, 0);
                }
            }
        }
    }
    #pragma unroll
    for (int mt = 0; mt < 4; ++mt) {
        #pragma unroll
        for (int nt = 0; nt < 4; ++nt) {
            int row0 = mi*128 + wm*64 + mt*16 + q*4;
            int col  = ni*128 + wn*64 + nt*16 + lm;
            float* rp = R  + (size_t)row0 * BAP + col;
            float* pp = Pm + (size_t)row0 * BAP + col;
            #pragma unroll
            for (int rr = 0; rr < 4; ++rr) {
                atomicAdd(rp + (size_t)rr * BAP, accR[mt][nt][rr]);
                atomicAdd(pp + (size_t)rr * BAP, accP[mt][nt][rr]);
            }
        }
    }
}

// ---------------- xd = DI * Hp^H rd ----------------
__global__ __launch_bounds__(256) void xd_init(const float* __restrict__ ay, const float* __restrict__ ax,
                                               const float* __restrict__ rd, float2* __restrict__ xd) {
    int j = blockIdx.x;
    int t = threadIdx.x;
    __shared__ float redr[256], redi[256];
    if (j >= 2000) { if (t == 0) xd[j] = make_float2(0.f, 0.f); return; }
    int jy = j % 40, jx = j / 40;
    float why = ((float)jy * (200.0f/39.0f) - 100.0f) * 1e-3f;
    float whx = ((float)jx * (200.0f/49.0f) - 100.0f) * 1e-3f;
    float sr = 0.f, si = 0.f;
    for (int i = t; i < KKTOT; i += 256) {
        float fr = phase_frac(ay[i]-why, ax[i]-whx);
        float r = rd[i];
        sr = fmaf(r, __builtin_amdgcn_cosf(fr), sr);
        si = fmaf(r, __builtin_amdgcn_sinf(fr), si);
    }
    redr[t] = sr; redi[t] = si;
    __syncthreads();
    for (int s2 = 128; s2 > 0; s2 >>= 1) {
        if (t < s2) { redr[t] += redr[t+s2]; redi[t] += redi[t+s2]; }
        __syncthreads();
    }
    if (t == 0) xd[j] = make_float2(0.01f * redr[0], -0.01f * redi[0]);
}

// ---------------- build G from upper-tri planes, Hermitian mirror ----------------
__global__ __launch_bounds__(256) void build_G_tile(const float* __restrict__ R, const float* __restrict__ Pm,
                                                    float2* __restrict__ G) {
    int ti = blockIdx.y, tj = blockIdx.x;
    if (tj < ti) return;
    __shared__ float2 tile[64][65];
    int t = threadIdx.x;
    #pragma unroll
    for (int r = 0; r < 16; ++r) {
        int e = t + 256*r;
        int lr = e >> 6, lc = e & 63;
        size_t mn = (size_t)(ti*64 + lr) * BAP + tj*64 + lc;
        float re = 0.01f * R[mn];
        float im = 0.01f * Pm[mn];
        G[mn] = make_float2(re, im);
        tile[lc][lr] = make_float2(re, -im);
    }
    if (tj == ti) return;
    __syncthreads();
    #pragma unroll
    for (int r = 0; r < 16; ++r) {
        int e = t + 256*r;
        int lr = e >> 6, lc = e & 63;
        G[(size_t)(tj*64 + lr) * BAP + ti*64 + lc] = tile[lr][lc];
    }
}

// ---------------- panel factorization + V = U^-1 (triangular inverse) ----------------
// T-recurrence is T·U = src with U upper-tri (U[j][j]=1+d_j, U[k][j]=Wp[k][j], k<j).
// Build V = U^-1 incrementally: V[i][j] = dinv_j*(delta_ij - M[i][j]),
// then M[i][c] += V[i][j]*rowj[c] for c>j.  panel_T becomes a dense GEMM.
__global__ __launch_bounds__(256) void panel_factor(const float2* __restrict__ G, const float2* __restrict__ xd,
                                                    float2* __restrict__ Vout, float2* __restrict__ vv,
                                                    float* __restrict__ sarr, int p0) {
    __shared__ float2 Rcm[64*65];   // Rcm[c*65+i] = R[i][c]
    __shared__ float2 M[64*64];     // becomes V
    __shared__ float2 rowj[64];
    __shared__ float2 xdp[64];
    int t = threadIdx.x;
    int i = t & 63, cg = t >> 6;
    int cbase = cg * 16;
    #pragma unroll
    for (int r = 0; r < 16; ++r) {
        int e = t + 256*r;
        int ci = e & 63, ri = e >> 6;
        Rcm[ci*65 + ri] = G[(size_t)(p0+ri)*BAP + p0 + ci];
        M[e] = make_float2(0.f, 0.f);
    }
    if (cg == 0) xdp[i] = xd[p0 + i];
    __syncthreads();
    for (int j = 0; j < 64; ++j) {
        // phase 1: reads only
        float2 pr = Rcm[j*65 + j];
        float dr = 1.0f + pr.x, dii = pr.y;
        float idn = 1.0f / (dr*dr + dii*dii);
        float2 dv = make_float2(dr*idn, -dii*idn);
        float2 col = Rcm[j*65 + i];
        float2 tp = cmulf(col, dv);
        float2 vj = xdp[j];
        float2 mij = M[i*64 + j];
        float2 Vij = cmulf(make_float2((i==j ? 1.0f : 0.0f) - mij.x, -mij.y), dv);
        if (i == j) {
            for (int c = cbase; c < cbase+16; ++c) rowj[c] = Rcm[c*65 + j];
            if (cg == 0) { vv[j] = vj; sarr[j] = dr; }
        }
        __syncthreads();
        // phase 2: writes
        M[i*64 + j] = Vij;                       // all col-groups write identical value
        for (int c = cbase; c < cbase+16; ++c) {
            float2 rj = rowj[c];
            float2 cur = Rcm[c*65 + i];
            cur.x -= tp.x*rj.x - tp.y*rj.y;
            cur.y -= tp.x*rj.y + tp.y*rj.x;
            Rcm[c*65 + i] = cur;
            if (c > j) {
                float2 m = M[i*64 + c];
                m.x += Vij.x*rj.x - Vij.y*rj.y;
                m.y += Vij.x*rj.y + Vij.y*rj.x;
                M[i*64 + c] = m;
            }
        }
        if (cg == 0) {
            float2 xi = xdp[i];
            xi.x -= tp.x*vj.x - tp.y*vj.y;
            xi.y -= tp.x*vj.y + tp.y*vj.x;
            xdp[i] = xi;
        }
        __syncthreads();
    }
    #pragma unroll
    for (int r = 0; r < 16; ++r) Vout[t + 256*r] = M[t + 256*r];
}

// ---------------- panel_T: dense T = src·V (2048x64x64) + xd -= T·v ----------------
__global__ __launch_bounds__(256) void panel_T(const float2* __restrict__ G, float2* __restrict__ xd,
                                               float2* __restrict__ T,
                                               const float2* __restrict__ V, const float2* __restrict__ vv, int p0) {
    __shared__ float srcRe[64][64];  // [k][ri] re/im split: conflict-free column reads
    __shared__ float srcIm[64][64];
    __shared__ float2 Vb[64*64];     // [k*64+j], read broadcast
    __shared__ float2 vb[64];
    __shared__ float2 xred[4][64];
    int t = threadIdx.x;
    int ri = t & 63, cg = t >> 6;
    int r = blockIdx.x * 64 + ri;
    {
        const float2* gp = G + (size_t)r * BAP + p0 + cg*16;
        #pragma unroll
        for (int k = 0; k < 16; ++k) {
            float2 g = gp[k];
            srcRe[cg*16 + k][ri] = g.x;
            srcIm[cg*16 + k][ri] = g.y;
        }
    }
    #pragma unroll
    for (int q = 0; q < 16; ++q) {
        int e = t + 256*q;
        Vb[e] = V[e];
    }
    if (cg == 0) vb[ri] = vv[ri];
    __syncthreads();
    int jb = cg * 16;
    float2 acc[16];
    #pragma unroll
    for (int jj = 0; jj < 16; ++jj) acc[jj] = make_float2(0.f, 0.f);
    for (int k = 0; k < 64; ++k) {
        float sx = srcRe[k][ri];
        float sy = srcIm[k][ri];
        #pragma unroll
        for (int jj = 0; jj < 16; ++jj) {
            float2 vk = Vb[k*64 + jb + jj];
            acc[jj].x = fmaf(sx, vk.x, fmaf(-sy, vk.y, acc[jj].x));
            acc[jj].y = fmaf(sx, vk.y, fmaf( sy, vk.x, acc[jj].y));
        }
    }
    float2 xp = make_float2(0.f, 0.f);
    #pragma unroll
    for (int jj = 0; jj < 16; ++jj) {
        T[(size_t)(jb + jj) * BAP + r] = acc[jj];
        float2 vj = vb[jb + jj];
        xp.x += acc[jj].x*vj.x - acc[jj].y*vj.y;
        xp.y += acc[jj].x*vj.y + acc[jj].y*vj.x;
    }
    xred[cg][ri] = xp;
    __syncthreads();
    if (cg == 0) {
        float2 x = xd[r];
        #pragma unroll
        for (int g = 0; g < 4; ++g) { x.x -= xred[g][ri].x; x.y -= xred[g][ri].y; }
        xd[r] = x;
    }
}

// ---------------- trailing update: G -= T*W, W[k][c] = s[k]*conj(T[k][c]) ----------------
__global__ __launch_bounds__(256) void trailing_update(float2* __restrict__ G,
                                                       const float2* __restrict__ T, const float* __restrict__ s) {
    __shared__ float2 Tb[16][128];
    __shared__ float2 Wb[16][64];
    int t = threadIdx.x;
    int cx = blockIdx.x * 64, ry = blockIdx.y * 128;
    int rq = t >> 4, cq = t & 15;
    float2 acc[8][4];
    #pragma unroll
    for (int si = 0; si < 8; ++si)
        #pragma unroll
        for (int u = 0; u < 4; ++u) acc[si][u] = make_float2(0.f, 0.f);

    for (int k0 = 0; k0 < 64; k0 += 16) {
        __syncthreads();
        #pragma unroll
        for (int r = 0; r < 4; ++r) {
            int e = t + 256*r;
            int k = e >> 6, x4 = e & 63;
            *(float4*)&Tb[k][x4*2] = *(const float4*)(T + (size_t)(k0+k) * BAP + ry + x4*2);
        }
        #pragma unroll
        for (int r = 0; r < 2; ++r) {
            int e = t + 256*r;
            int k = e >> 5, x4 = e & 31;
            float sk = s[k0+k];
            float4 tv = *(const float4*)(T + (size_t)(k0+k) * BAP + cx + x4*2);
            Wb[k][x4*2]   = make_float2(tv.x*sk, -tv.y*sk);
            Wb[k][x4*2+1] = make_float2(tv.z*sk, -tv.w*sk);
        }
        __syncthreads();
        #pragma unroll
        for (int k = 0; k < 16; ++k) {
            float2 av[8], bv[4];
            #pragma unroll
            for (int si = 0; si < 8; ++si) av[si] = Tb[k][rq + 16*si];
            #pragma unroll
            for (int u = 0; u < 4; ++u) bv[u] = Wb[k][cq + 16*u];
            #pragma unroll
            for (int si = 0; si < 8; ++si)
                #pragma unroll
                for (int u = 0; u < 4; ++u) {
                    acc[si][u].x = fmaf(av[si].x, bv[u].x, fmaf(-av[si].y, bv[u].y, acc[si][u].x));
                    acc[si][u].y = fmaf(av[si].x, bv[u].y, fmaf( av[si].y, bv[u].x, acc[si][u].y));
                }
        }
    }
    #pragma unroll
    for (int si = 0; si < 8; ++si) {
        float2* gp = G + (size_t)(ry + rq + 16*si) * BAP + cx + cq;
        #pragma unroll
        for (int u = 0; u < 4; ++u) {
            float2 gg = gp[16*u];
            gg.x -= acc[si][u].x;
            gg.y -= acc[si][u].y;
            gp[16*u] = gg;
        }
    }
}

// ---------------- finalize ----------------
__global__ __launch_bounds__(256) void finalize_k(const float2* __restrict__ G, const float2* __restrict__ xd,
                                                  float* __restrict__ out, int out_size) {
    int o = blockIdx.x * 256 + threadIdx.x;
    if (o >= 2000) return;
    int b = o / 50, a = o % 50;
    int j = b * 50 + (49 - a);
    float2 x = xd[j];
    float2 g = G[(size_t)j * BAP + j];
    float den = 1.0f / (g.x*g.x + g.y*g.y);
    float re = (x.x*g.x + x.y*g.y) * den;
    float im = (x.y*g.x - x.x*g.y) * den;
    out[o] = re;
    if (out_size >= 4000) out[2000 + o] = im;
}

extern "C" void kernel_launch(void* const* d_in, const int* in_sizes, int n_in,
                              void* d_out, int out_size, void* d_ws, size_t ws_size,
                              hipStream_t stream) {
    const float* sar = (const float*)d_in[0];
    const int*   py  = (const int*)d_in[1];
    float* out = (float*)d_out;
    char* w = (char*)d_ws;
    size_t off = 0;
    auto take = [&](size_t sz) -> char* { char* p = w + off; off += (sz + 255) & ~(size_t)255; return p; };

    float*  R   = (float*)take((size_t)BAP*BAP*4);
    float*  Pm  = (float*)take((size_t)BAP*BAP*4);
    float2* G  = (float2*)take((size_t)BAP*BAP*8);
    float2* T  = (float2*)take((size_t)64*BAP*8);
    float2* xd = (float2*)take((size_t)BAP*8);
    float*  ay = (float*)take((size_t)KPADMAX*4);
    float*  ax = (float*)take((size_t)KPADMAX*4);
    float*  rd = (float*)take((size_t)KPADMAX*4);
    float2* Vp = (float2*)take(64*64*8);
    float2* vv   = (float2*)take(64*8);
    float*  sarr = (float*)take(64*4);

    size_t avail = (ws_size > off + 4096) ? (ws_size - off - 4096) : 0;
    long long Kc = (long long)(avail / 8192) & ~2047LL;
    if (Kc > KPADMAX) Kc = KPADMAX;
    if (Kc < 2048) Kc = 2048;
    int nch = (int)((KKTOT + Kc - 1) / Kc);
    long long Kc2 = 2048LL * ((KKTOT + (long long)nch*2048 - 1) / ((long long)nch*2048));
    if (Kc2 >= 2048 && Kc2 <= Kc) Kc = Kc2;
    _Float16* C = (_Float16*)take((size_t)BAP * Kc * 2);
    _Float16* S = (_Float16*)take((size_t)BAP * Kc * 2);
    int kiters = (int)(Kc / 64);

    hipMemsetAsync(R, 0, (size_t)BAP*BAP*4*2, stream);  // R, Pm contiguous

    decode_k<<<dim3(391), dim3(256), 0, stream>>>(sar, py, ay, ax, rd);
    xd_init<<<dim3(BAP), dim3(256), 0, stream>>>(ay, ax, rd, xd);

    for (int c0 = 0; c0 < nch; ++c0) {
        gen_cs<<<dim3((unsigned)(Kc/2048), BAP), dim3(256), 0, stream>>>(C, S, ay, ax, (int)(c0*Kc), (int)Kc);
        gemm_ut<<<dim3(136, 8), dim3(256), 0, stream>>>(C, S, R, Pm, kiters, (int)Kc);
    }
    build_G_tile<<<dim3(32, 32), dim3(256), 0, stream>>>(R, Pm, G);

    for (int p = 0; p < 32; ++p) {
        int p0 = p * 64;
        panel_factor<<<dim3(1), dim3(256), 0, stream>>>(G, xd, Vp, vv, sarr, p0);
        panel_T<<<dim3(32), dim3(256), 0, stream>>>(G, xd, T, Vp, vv, p0);
        trailing_update<<<dim3(32, 16), dim3(256), 0, stream>>>(G, T, sarr);
    }
    finalize_k<<<dim3(8), dim3(256), 0, stream>>>(G, xd, out, out_size);
}

// Round 12
// 8674.725 us; speedup vs baseline: 1.2881x; 1.2881x over previous
//
#include <hip/hip_runtime.h>
#include <hip/hip_bf16.h>
#include <stdint.h>

#define KKTOT 100000
#define BAP   2048
#define KPADMAX 100352   // 49*2048

typedef _Float16 f16x8 __attribute__((ext_vector_type(8)));
typedef float    f32x4 __attribute__((ext_vector_type(4)));

// ---- constants (match reference f32 arithmetic) ----
__device__ __constant__ float KCf  = (float)(4.0 * 3.14159265358979323846 * 77.0e9 / 299792458.0);
__device__ __constant__ float I2PA = (float)(0.15915494309189534940823);
__device__ __constant__ float I2PB = (float)(0.15915494309189534940823 - (double)(float)(0.15915494309189534940823));

__device__ __forceinline__ float phase_frac(float dy, float dxx) {
    float d2 = fmaf(dy, dy, fmaf(dxx, dxx, 0.09f));
    float ph = KCf * sqrtf(d2);
    float h  = ph * I2PA;
    float l  = fmaf(ph, I2PA, -h);
    l = fmaf(ph, I2PB, l);
    return (h - floorf(h)) + l;                  // revolutions
}

__device__ __forceinline__ void gload16(const void* g, void* l) {
    __builtin_amdgcn_global_load_lds(
        (__attribute__((address_space(1))) void*)(uintptr_t)g,
        (__attribute__((address_space(3))) void*)(uint32_t)(uintptr_t)l,
        16, 0, 0);
}

__device__ __forceinline__ float2 cmulf(float2 a, float2 b) {
    return make_float2(a.x*b.x - a.y*b.y, a.x*b.y + a.y*b.x);
}

// ---------------- decode py (int32) ----------------
__global__ __launch_bounds__(256) void decode_k(const float* __restrict__ sar, const int* __restrict__ py,
                                                float* __restrict__ ay, float* __restrict__ ax, float* __restrict__ rd) {
    int i = blockIdx.x * 256 + threadIdx.x;
    if (i >= KKTOT) return;
    int p = py[i];
    int iy = p & 511, ix = p >> 9;
    ay[i] = ((float)iy + 0.5f - 256.0f) * 1e-3f;
    ax[i] = ((float)ix + 0.5f - 256.0f) * 1e-3f;
    rd[i] = sar[p];
}

// ---------------- generate C=cos, S=sin as f16, layout [2048][Kc] ----------------
__global__ __launch_bounds__(256) void gen_cs(_Float16* __restrict__ C, _Float16* __restrict__ S,
                                              const float* __restrict__ ay, const float* __restrict__ ax,
                                              int k0, int Kc) {
    int j = blockIdx.y;
    long long kk = ((long long)blockIdx.x * 256 + threadIdx.x) * 8;
    size_t o = (size_t)j * Kc + kk;
    long long kg = (long long)k0 + kk;
    f16x8 cv, sv;
    if (j < 2000 && kg < KKTOT) {
        int jy = j % 40, jx = j / 40;
        float why = ((float)jy * (200.0f/39.0f) - 100.0f) * 1e-3f;   // wh2[jy]
        float whx = ((float)jx * (200.0f/49.0f) - 100.0f) * 1e-3f;   // wh1[jx]
        float4 a0 = *(const float4*)(ay + kg);
        float4 a1 = *(const float4*)(ay + kg + 4);
        float4 b0 = *(const float4*)(ax + kg);
        float4 b1 = *(const float4*)(ax + kg + 4);
        float ayv[8] = {a0.x,a0.y,a0.z,a0.w,a1.x,a1.y,a1.z,a1.w};
        float axv[8] = {b0.x,b0.y,b0.z,b0.w,b1.x,b1.y,b1.z,b1.w};
        #pragma unroll
        for (int e = 0; e < 8; ++e) {
            float fr = phase_frac(ayv[e]-why, axv[e]-whx);
            cv[e] = (_Float16)__builtin_amdgcn_cosf(fr);
            sv[e] = (_Float16)__builtin_amdgcn_sinf(fr);
        }
    } else {
        #pragma unroll
        for (int e = 0; e < 8; ++e) { cv[e] = (_Float16)0.f; sv[e] = (_Float16)0.f; }
    }
    *(f16x8*)(C + o) = cv;
    *(f16x8*)(S + o) = sv;
}

// ---------------- UPPER-TRIANGLE fused Gram GEMM (compact grid, z=16, atomic epilogue) ----------------
__global__ __launch_bounds__(256) void gemm_ut(const _Float16* __restrict__ C, const _Float16* __restrict__ S,
                                               float* __restrict__ R, float* __restrict__ Pm,
                                               int kiters, int kstride) {
    int rem = blockIdx.x;
    int mi = 0;
    #pragma unroll
    for (int r = 0; r < 16; ++r) {
        int cnt = 16 - r;
        if (rem < cnt) { mi = r; break; }
        rem -= cnt;
    }
    const int ni = mi + rem;
    const int z = blockIdx.y;

    __shared__ _Float16 ldsCa[8192];
    __shared__ _Float16 ldsSa[8192];
    __shared__ _Float16 ldsCb[8192];
    __shared__ _Float16 ldsSb[8192];
    const int t = threadIdx.x;
    const int w = t >> 6;
    const int lane = t & 63;

    f32x4 accR[4][4], accP[4][4];
    #pragma unroll
    for (int a = 0; a < 4; ++a)
        #pragma unroll
        for (int b = 0; b < 4; ++b) { accR[a][b] = (f32x4){0.f,0.f,0.f,0.f}; accP[a][b] = (f32x4){0.f,0.f,0.f,0.f}; }

    size_t aoff[4], boff[4];
    #pragma unroll
    for (int r = 0; r < 4; ++r) {
        int c = r * 256 + t;
        int jl = c >> 3;
        int ks = (c & 7) ^ (jl & 7);
        aoff[r] = (size_t)(mi*128 + jl) * kstride + ks*8;
        boff[r] = (size_t)(ni*128 + jl) * kstride + ks*8;
    }
    const int wm = w & 1, wn = w >> 1;
    const int q = lane >> 4, lm = lane & 15;
    const int ajl = wm*64 + lm;
    const int aoffl = (ajl*8 + (q ^ (ajl & 7))) * 16;
    const int bjl = wn*64 + lm;
    const int boffl = (bjl*8 + (q ^ (bjl & 7))) * 16;

    const int kq = kiters >> 4;        // kiters multiple of 32 (Kc mult of 2048)
    for (int kt = z*kq; kt < (z+1)*kq; ++kt) {
        __syncthreads();
        const _Float16* gc = C + (size_t)kt * 64;
        const _Float16* gs = S + (size_t)kt * 64;
        #pragma unroll
        for (int r = 0; r < 4; ++r) {
            size_t dst = (size_t)(r*256 + w*64)*16;
            gload16(gc + aoff[r], (char*)ldsCa + dst);
            gload16(gs + aoff[r], (char*)ldsSa + dst);
            gload16(gc + boff[r], (char*)ldsCb + dst);
            gload16(gs + boff[r], (char*)ldsSb + dst);
        }
        __syncthreads();
        #pragma unroll
        for (int ks = 0; ks < 2; ++ks) {
            f16x8 bfC[4], bfS[4];
            #pragma unroll
            for (int nt = 0; nt < 4; ++nt) {
                bfC[nt] = *(const f16x8*)((const char*)ldsCb + ((boffl ^ (ks*64)) + nt*2048));
                bfS[nt] = *(const f16x8*)((const char*)ldsSb + ((boffl ^ (ks*64)) + nt*2048));
            }
            #pragma unroll
            for (int mt = 0; mt < 4; ++mt) {
                f16x8 afC = *(const f16x8*)((const char*)ldsCa + ((aoffl ^ (ks*64)) + mt*2048));
                f16x8 afS = *(const f16x8*)((const char*)ldsSa + ((aoffl ^ (ks*64)) + mt*2048));
                f16x8 nfS;
                #pragma unroll
                for (int e = 0; e < 8; ++e) nfS[e] = -afS[e];
                #pragma unroll
                for (int nt = 0; nt < 4; ++nt) {
                    accR[mt][nt] = __builtin_amdgcn_mfma_f32_16x16x32_f16(afC, bfC[nt], accR[mt][nt], 0, 0, 0);
                    accR[mt][nt] = __builtin_amdgcn_mfma_f32_16x16x32_f16(afS, bfS[nt], accR[mt][nt], 0, 0, 0);
                    accP[mt][nt] = __builtin_amdgcn_mfma_f32_16x16x32_f16(afC, bfS[nt], accP[mt][nt], 0, 0, 0);
                    accP[mt][nt] = __builtin_amdgcn_mfma_f32_16x16x32_f16(nfS, bfC[nt], accP[mt][nt], 0, 0, 0);
                }
            }
        }
    }
    #pragma unroll
    for (int mt = 0; mt < 4; ++mt) {
        #pragma unroll
        for (int nt = 0; nt < 4; ++nt) {
            int row0 = mi*128 + wm*64 + mt*16 + q*4;
            int col  = ni*128 + wn*64 + nt*16 + lm;
            float* rp = R  + (size_t)row0 * BAP + col;
            float* pp = Pm + (size_t)row0 * BAP + col;
            #pragma unroll
            for (int rr = 0; rr < 4; ++rr) {
                atomicAdd(rp + (size_t)rr * BAP, accR[mt][nt][rr]);
                atomicAdd(pp + (size_t)rr * BAP, accP[mt][nt][rr]);
            }
        }
    }
}

// ---------------- xd = DI * Hp^H rd ----------------
__global__ __launch_bounds__(256) void xd_init(const float* __restrict__ ay, const float* __restrict__ ax,
                                               const float* __restrict__ rd, float2* __restrict__ xd) {
    int j = blockIdx.x;
    int t = threadIdx.x;
    __shared__ float redr[256], redi[256];
    if (j >= 2000) { if (t == 0) xd[j] = make_float2(0.f, 0.f); return; }
    int jy = j % 40, jx = j / 40;
    float why = ((float)jy * (200.0f/39.0f) - 100.0f) * 1e-3f;
    float whx = ((float)jx * (200.0f/49.0f) - 100.0f) * 1e-3f;
    float sr = 0.f, si = 0.f;
    for (int i = t; i < KKTOT; i += 256) {
        float fr = phase_frac(ay[i]-why, ax[i]-whx);
        float r = rd[i];
        sr = fmaf(r, __builtin_amdgcn_cosf(fr), sr);
        si = fmaf(r, __builtin_amdgcn_sinf(fr), si);
    }
    redr[t] = sr; redi[t] = si;
    __syncthreads();
    for (int s2 = 128; s2 > 0; s2 >>= 1) {
        if (t < s2) { redr[t] += redr[t+s2]; redi[t] += redi[t+s2]; }
        __syncthreads();
    }
    if (t == 0) xd[j] = make_float2(0.01f * redr[0], -0.01f * redi[0]);
}

// ---------------- build G from upper-tri planes, Hermitian mirror ----------------
__global__ __launch_bounds__(256) void build_G_tile(const float* __restrict__ R, const float* __restrict__ Pm,
                                                    float2* __restrict__ G) {
    int ti = blockIdx.y, tj = blockIdx.x;
    if (tj < ti) return;
    __shared__ float2 tile[64][65];
    int t = threadIdx.x;
    #pragma unroll
    for (int r = 0; r < 16; ++r) {
        int e = t + 256*r;
        int lr = e >> 6, lc = e & 63;
        size_t mn = (size_t)(ti*64 + lr) * BAP + tj*64 + lc;
        float re = 0.01f * R[mn];
        float im = 0.01f * Pm[mn];
        G[mn] = make_float2(re, im);
        tile[lc][lr] = make_float2(re, -im);
    }
    if (tj == ti) return;
    __syncthreads();
    #pragma unroll
    for (int r = 0; r < 16; ++r) {
        int e = t + 256*r;
        int lr = e >> 6, lc = e & 63;
        G[(size_t)(tj*64 + lr) * BAP + ti*64 + lc] = tile[lr][lc];
    }
}

// ---------------- panel factorization + V = U^-1 (triangular inverse) ----------------
// M stored COLUMN-MAJOR padded (Mcm[c*65+i]) — lanes vary i => conflict-free
// (r11's row-major M[i*64+c] was a 32-way bank conflict: all lanes hit bank 2c%32).
__global__ __launch_bounds__(256) void panel_factor(const float2* __restrict__ G, const float2* __restrict__ xd,
                                                    float2* __restrict__ Vout, float2* __restrict__ vv,
                                                    float* __restrict__ sarr, int p0) {
    __shared__ float2 Rcm[64*65];   // Rcm[c*65+i] = R[i][c]
    __shared__ float2 Mcm[64*65];   // Mcm[c*65+i] = M[i][c], becomes V
    __shared__ float2 rowj[64];
    __shared__ float2 xdp[64];
    int t = threadIdx.x;
    int i = t & 63, cg = t >> 6;
    int cbase = cg * 16;
    #pragma unroll
    for (int r = 0; r < 16; ++r) {
        int e = t + 256*r;
        int ci = e & 63, ri = e >> 6;
        Rcm[ci*65 + ri] = G[(size_t)(p0+ri)*BAP + p0 + ci];
    }
    #pragma unroll
    for (int r = 0; r < 17; ++r) {
        int e = t + 256*r;
        if (e < 64*65) Mcm[e] = make_float2(0.f, 0.f);
    }
    if (cg == 0) xdp[i] = xd[p0 + i];
    __syncthreads();
    for (int j = 0; j < 64; ++j) {
        // phase 1: reads only
        float2 pr = Rcm[j*65 + j];
        float dr = 1.0f + pr.x, dii = pr.y;
        float idn = 1.0f / (dr*dr + dii*dii);
        float2 dv = make_float2(dr*idn, -dii*idn);
        float2 col = Rcm[j*65 + i];
        float2 tp = cmulf(col, dv);
        float2 vj = xdp[j];
        float2 mij = Mcm[j*65 + i];
        float2 Vij = cmulf(make_float2((i==j ? 1.0f : 0.0f) - mij.x, -mij.y), dv);
        if (i == j) {
            for (int c = cbase; c < cbase+16; ++c) rowj[c] = Rcm[c*65 + j];
            if (cg == 0) { vv[j] = vj; sarr[j] = dr; }
        }
        __syncthreads();
        // phase 2: writes
        Mcm[j*65 + i] = Vij;                     // all col-groups write identical value
        for (int c = cbase; c < cbase+16; ++c) {
            float2 rj = rowj[c];
            float2 cur = Rcm[c*65 + i];
            cur.x -= tp.x*rj.x - tp.y*rj.y;
            cur.y -= tp.x*rj.y + tp.y*rj.x;
            Rcm[c*65 + i] = cur;
            if (c > j) {
                float2 m = Mcm[c*65 + i];
                m.x += Vij.x*rj.x - Vij.y*rj.y;
                m.y += Vij.x*rj.y + Vij.y*rj.x;
                Mcm[c*65 + i] = m;
            }
        }
        if (cg == 0) {
            float2 xi = xdp[i];
            xi.x -= tp.x*vj.x - tp.y*vj.y;
            xi.y -= tp.x*vj.y + tp.y*vj.x;
            xdp[i] = xi;
        }
        __syncthreads();
    }
    // export V[i][j] = Mcm[j*65+i]; Vout indexed V[k*64+j] (row-major)
    #pragma unroll
    for (int r = 0; r < 16; ++r) {
        int e = t + 256*r;
        int ri = e >> 6, ci = e & 63;
        Vout[e] = Mcm[ci*65 + ri];
    }
}

// ---------------- panel_T: dense T = src·V (2048x64x64) + xd -= T·v ----------------
__global__ __launch_bounds__(256) void panel_T(const float2* __restrict__ G, float2* __restrict__ xd,
                                               float2* __restrict__ T,
                                               const float2* __restrict__ V, const float2* __restrict__ vv, int p0) {
    __shared__ float srcRe[64][64];
    __shared__ float srcIm[64][64];
    __shared__ float2 Vb[64*64];
    __shared__ float2 vb[64];
    __shared__ float2 xred[4][64];
    int t = threadIdx.x;
    int ri = t & 63, cg = t >> 6;
    int r = blockIdx.x * 64 + ri;
    {
        const float2* gp = G + (size_t)r * BAP + p0 + cg*16;
        #pragma unroll
        for (int k = 0; k < 16; ++k) {
            float2 g = gp[k];
            srcRe[cg*16 + k][ri] = g.x;
            srcIm[cg*16 + k][ri] = g.y;
        }
    }
    #pragma unroll
    for (int q = 0; q < 16; ++q) {
        int e = t + 256*q;
        Vb[e] = V[e];
    }
    if (cg == 0) vb[ri] = vv[ri];
    __syncthreads();
    int jb = cg * 16;
    float2 acc[16];
    #pragma unroll
    for (int jj = 0; jj < 16; ++jj) acc[jj] = make_float2(0.f, 0.f);
    for (int k = 0; k < 64; ++k) {
        float sx = srcRe[k][ri];
        float sy = srcIm[k][ri];
        #pragma unroll
        for (int jj = 0; jj < 16; ++jj) {
            float2 vk = Vb[k*64 + jb + jj];
            acc[jj].x = fmaf(sx, vk.x, fmaf(-sy, vk.y, acc[jj].x));
            acc[jj].y = fmaf(sx, vk.y, fmaf( sy, vk.x, acc[jj].y));
        }
    }
    float2 xp = make_float2(0.f, 0.f);
    #pragma unroll
    for (int jj = 0; jj < 16; ++jj) {
        T[(size_t)(jb + jj) * BAP + r] = acc[jj];
        float2 vj = vb[jb + jj];
        xp.x += acc[jj].x*vj.x - acc[jj].y*vj.y;
        xp.y += acc[jj].x*vj.y + acc[jj].y*vj.x;
    }
    xred[cg][ri] = xp;
    __syncthreads();
    if (cg == 0) {
        float2 x = xd[r];
        #pragma unroll
        for (int g = 0; g < 4; ++g) { x.x -= xred[g][ri].x; x.y -= xred[g][ri].y; }
        xd[r] = x;
    }
}

// ---------------- trailing update: G -= T*W on FUTURE columns only ----------------
// W[k][c] = s[k]*conj(T[k][c]); cx offset by coff tiles (c >= p0+64).
__global__ __launch_bounds__(256) void trailing_update(float2* __restrict__ G,
                                                       const float2* __restrict__ T, const float* __restrict__ s,
                                                       int coff) {
    __shared__ float2 Tb[16][128];
    __shared__ float2 Wb[16][64];
    int t = threadIdx.x;
    int cx = (blockIdx.x + coff) * 64, ry = blockIdx.y * 128;
    int rq = t >> 4, cq = t & 15;
    float2 acc[8][4];
    #pragma unroll
    for (int si = 0; si < 8; ++si)
        #pragma unroll
        for (int u = 0; u < 4; ++u) acc[si][u] = make_float2(0.f, 0.f);

    for (int k0 = 0; k0 < 64; k0 += 16) {
        __syncthreads();
        #pragma unroll
        for (int r = 0; r < 4; ++r) {
            int e = t + 256*r;
            int k = e >> 6, x4 = e & 63;
            *(float4*)&Tb[k][x4*2] = *(const float4*)(T + (size_t)(k0+k) * BAP + ry + x4*2);
        }
        #pragma unroll
        for (int r = 0; r < 2; ++r) {
            int e = t + 256*r;
            int k = e >> 5, x4 = e & 31;
            float sk = s[k0+k];
            float4 tv = *(const float4*)(T + (size_t)(k0+k) * BAP + cx + x4*2);
            Wb[k][x4*2]   = make_float2(tv.x*sk, -tv.y*sk);
            Wb[k][x4*2+1] = make_float2(tv.z*sk, -tv.w*sk);
        }
        __syncthreads();
        #pragma unroll
        for (int k = 0; k < 16; ++k) {
            float2 av[8], bv[4];
            #pragma unroll
            for (int si = 0; si < 8; ++si) av[si] = Tb[k][rq + 16*si];
            #pragma unroll
            for (int u = 0; u < 4; ++u) bv[u] = Wb[k][cq + 16*u];
            #pragma unroll
            for (int si = 0; si < 8; ++si)
                #pragma unroll
                for (int u = 0; u < 4; ++u) {
                    acc[si][u].x = fmaf(av[si].x, bv[u].x, fmaf(-av[si].y, bv[u].y, acc[si][u].x));
                    acc[si][u].y = fmaf(av[si].x, bv[u].y, fmaf( av[si].y, bv[u].x, acc[si][u].y));
                }
        }
    }
    #pragma unroll
    for (int si = 0; si < 8; ++si) {
        float2* gp = G + (size_t)(ry + rq + 16*si) * BAP + cx + cq;
        #pragma unroll
        for (int u = 0; u < 4; ++u) {
            float2 gg = gp[16*u];
            gg.x -= acc[si][u].x;
            gg.y -= acc[si][u].y;
            gp[16*u] = gg;
        }
    }
}

// ---------------- diag_fix: past diagonals G[j][j] -= sum_k s_k|T[k][j]|^2 (real) ----------------
__global__ __launch_bounds__(256) void diag_fix(float2* __restrict__ G, const float2* __restrict__ T,
                                                const float* __restrict__ s, int jmax) {
    int j = blockIdx.x * 256 + threadIdx.x;
    if (j >= jmax) return;
    float acc = 0.f;
    for (int k = 0; k < 64; ++k) {
        float2 t = T[(size_t)k * BAP + j];
        acc = fmaf(s[k], fmaf(t.x, t.x, t.y*t.y), acc);
    }
    size_t jj = (size_t)j * BAP + j;
    float2 g = G[jj];
    g.x -= acc;
    G[jj] = g;
}

// ---------------- finalize ----------------
__global__ __launch_bounds__(256) void finalize_k(const float2* __restrict__ G, const float2* __restrict__ xd,
                                                  float* __restrict__ out, int out_size) {
    int o = blockIdx.x * 256 + threadIdx.x;
    if (o >= 2000) return;
    int b = o / 50, a = o % 50;
    int j = b * 50 + (49 - a);
    float2 x = xd[j];
    float2 g = G[(size_t)j * BAP + j];
    float den = 1.0f / (g.x*g.x + g.y*g.y);
    float re = (x.x*g.x + x.y*g.y) * den;
    float im = (x.y*g.x - x.x*g.y) * den;
    out[o] = re;
    if (out_size >= 4000) out[2000 + o] = im;
}

extern "C" void kernel_launch(void* const* d_in, const int* in_sizes, int n_in,
                              void* d_out, int out_size, void* d_ws, size_t ws_size,
                              hipStream_t stream) {
    const float* sar = (const float*)d_in[0];
    const int*   py  = (const int*)d_in[1];
    float* out = (float*)d_out;
    char* w = (char*)d_ws;
    size_t off = 0;
    auto take = [&](size_t sz) -> char* { char* p = w + off; off += (sz + 255) & ~(size_t)255; return p; };

    float*  R   = (float*)take((size_t)BAP*BAP*4);
    float*  Pm  = (float*)take((size_t)BAP*BAP*4);
    float2* G  = (float2*)take((size_t)BAP*BAP*8);
    float2* T  = (float2*)take((size_t)64*BAP*8);
    float2* xd = (float2*)take((size_t)BAP*8);
    float*  ay = (float*)take((size_t)KPADMAX*4);
    float*  ax = (float*)take((size_t)KPADMAX*4);
    float*  rd = (float*)take((size_t)KPADMAX*4);
    float2* Vp = (float2*)take(64*64*8);
    float2* vv   = (float2*)take(64*8);
    float*  sarr = (float*)take(64*4);

    size_t avail = (ws_size > off + 4096) ? (ws_size - off - 4096) : 0;
    long long Kc = (long long)(avail / 8192) & ~2047LL;
    if (Kc > KPADMAX) Kc = KPADMAX;
    if (Kc < 2048) Kc = 2048;
    int nch = (int)((KKTOT + Kc - 1) / Kc);
    long long Kc2 = 2048LL * ((KKTOT + (long long)nch*2048 - 1) / ((long long)nch*2048));
    if (Kc2 >= 2048 && Kc2 <= Kc) Kc = Kc2;
    _Float16* C = (_Float16*)take((size_t)BAP * Kc * 2);
    _Float16* S = (_Float16*)take((size_t)BAP * Kc * 2);
    int kiters = (int)(Kc / 64);

    hipMemsetAsync(R, 0, (size_t)BAP*BAP*4*2, stream);  // R, Pm contiguous

    decode_k<<<dim3(391), dim3(256), 0, stream>>>(sar, py, ay, ax, rd);
    xd_init<<<dim3(BAP), dim3(256), 0, stream>>>(ay, ax, rd, xd);

    for (int c0 = 0; c0 < nch; ++c0) {
        gen_cs<<<dim3((unsigned)(Kc/2048), BAP), dim3(256), 0, stream>>>(C, S, ay, ax, (int)(c0*Kc), (int)Kc);
        gemm_ut<<<dim3(136, 16), dim3(256), 0, stream>>>(C, S, R, Pm, kiters, (int)Kc);
    }
    build_G_tile<<<dim3(32, 32), dim3(256), 0, stream>>>(R, Pm, G);

    for (int p = 0; p < 32; ++p) {
        int p0 = p * 64;
        panel_factor<<<dim3(1), dim3(256), 0, stream>>>(G, xd, Vp, vv, sarr, p0);
        panel_T<<<dim3(32), dim3(256), 0, stream>>>(G, xd, T, Vp, vv, p0);
        if (p < 31)
            trailing_update<<<dim3(31 - p, 16), dim3(256), 0, stream>>>(G, T, sarr, p + 1);
        diag_fix<<<dim3((p0 + 64 + 255) / 256), dim3(256), 0, stream>>>(G, T, sarr, p0 + 64);
    }
    finalize_k<<<dim3(8), dim3(256), 0, stream>>>(G, xd, out, out_size);
}

// Round 13
// 5982.498 us; speedup vs baseline: 1.8678x; 1.4500x over previous
//
#include <hip/hip_runtime.h>
#include <hip/hip_bf16.h>
#include <stdint.h>

#define KKTOT 100000
#define BAP   2048
#define KPADMAX 100352   // 49*2048

typedef _Float16 f16x8 __attribute__((ext_vector_type(8)));
typedef float    f32x4 __attribute__((ext_vector_type(4)));

// ---- constants (match reference f32 arithmetic) ----
__device__ __constant__ float KCf  = (float)(4.0 * 3.14159265358979323846 * 77.0e9 / 299792458.0);
__device__ __constant__ float I2PA = (float)(0.15915494309189534940823);
__device__ __constant__ float I2PB = (float)(0.15915494309189534940823 - (double)(float)(0.15915494309189534940823));

__device__ __forceinline__ float phase_frac(float dy, float dxx) {
    float d2 = fmaf(dy, dy, fmaf(dxx, dxx, 0.09f));
    float ph = KCf * sqrtf(d2);
    float h  = ph * I2PA;
    float l  = fmaf(ph, I2PA, -h);
    l = fmaf(ph, I2PB, l);
    return (h - floorf(h)) + l;                  // revolutions
}

__device__ __forceinline__ void gload16(const void* g, void* l) {
    __builtin_amdgcn_global_load_lds(
        (__attribute__((address_space(1))) void*)(uintptr_t)g,
        (__attribute__((address_space(3))) void*)(uint32_t)(uintptr_t)l,
        16, 0, 0);
}

__device__ __forceinline__ float2 cmulf(float2 a, float2 b) {
    return make_float2(a.x*b.x - a.y*b.y, a.x*b.y + a.y*b.x);
}

// ---------------- decode py (int32) ----------------
__global__ __launch_bounds__(256) void decode_k(const float* __restrict__ sar, const int* __restrict__ py,
                                                float* __restrict__ ay, float* __restrict__ ax, float* __restrict__ rd) {
    int i = blockIdx.x * 256 + threadIdx.x;
    if (i >= KKTOT) return;
    int p = py[i];
    int iy = p & 511, ix = p >> 9;
    ay[i] = ((float)iy + 0.5f - 256.0f) * 1e-3f;
    ax[i] = ((float)ix + 0.5f - 256.0f) * 1e-3f;
    rd[i] = sar[p];
}

// ---------------- generate C=cos, S=sin as f16, layout [2048][Kc] ----------------
__global__ __launch_bounds__(256) void gen_cs(_Float16* __restrict__ C, _Float16* __restrict__ S,
                                              const float* __restrict__ ay, const float* __restrict__ ax,
                                              int k0, int Kc) {
    int j = blockIdx.y;
    long long kk = ((long long)blockIdx.x * 256 + threadIdx.x) * 8;
    size_t o = (size_t)j * Kc + kk;
    long long kg = (long long)k0 + kk;
    f16x8 cv, sv;
    if (j < 2000 && kg < KKTOT) {
        int jy = j % 40, jx = j / 40;
        float why = ((float)jy * (200.0f/39.0f) - 100.0f) * 1e-3f;   // wh2[jy]
        float whx = ((float)jx * (200.0f/49.0f) - 100.0f) * 1e-3f;   // wh1[jx]
        float4 a0 = *(const float4*)(ay + kg);
        float4 a1 = *(const float4*)(ay + kg + 4);
        float4 b0 = *(const float4*)(ax + kg);
        float4 b1 = *(const float4*)(ax + kg + 4);
        float ayv[8] = {a0.x,a0.y,a0.z,a0.w,a1.x,a1.y,a1.z,a1.w};
        float axv[8] = {b0.x,b0.y,b0.z,b0.w,b1.x,b1.y,b1.z,b1.w};
        #pragma unroll
        for (int e = 0; e < 8; ++e) {
            float fr = phase_frac(ayv[e]-why, axv[e]-whx);
            cv[e] = (_Float16)__builtin_amdgcn_cosf(fr);
            sv[e] = (_Float16)__builtin_amdgcn_sinf(fr);
        }
    } else {
        #pragma unroll
        for (int e = 0; e < 8; ++e) { cv[e] = (_Float16)0.f; sv[e] = (_Float16)0.f; }
    }
    *(f16x8*)(C + o) = cv;
    *(f16x8*)(S + o) = sv;
}

// ---------------- UPPER-TRIANGLE fused Gram GEMM (compact grid, z=16, atomic epilogue) ----------------
__global__ __launch_bounds__(256) void gemm_ut(const _Float16* __restrict__ C, const _Float16* __restrict__ S,
                                               float* __restrict__ R, float* __restrict__ Pm,
                                               int kiters, int kstride) {
    int rem = blockIdx.x;
    int mi = 0;
    #pragma unroll
    for (int r = 0; r < 16; ++r) {
        int cnt = 16 - r;
        if (rem < cnt) { mi = r; break; }
        rem -= cnt;
    }
    const int ni = mi + rem;
    const int z = blockIdx.y;

    __shared__ _Float16 ldsCa[8192];
    __shared__ _Float16 ldsSa[8192];
    __shared__ _Float16 ldsCb[8192];
    __shared__ _Float16 ldsSb[8192];
    const int t = threadIdx.x;
    const int w = t >> 6;
    const int lane = t & 63;

    f32x4 accR[4][4], accP[4][4];
    #pragma unroll
    for (int a = 0; a < 4; ++a)
        #pragma unroll
        for (int b = 0; b < 4; ++b) { accR[a][b] = (f32x4){0.f,0.f,0.f,0.f}; accP[a][b] = (f32x4){0.f,0.f,0.f,0.f}; }

    size_t aoff[4], boff[4];
    #pragma unroll
    for (int r = 0; r < 4; ++r) {
        int c = r * 256 + t;
        int jl = c >> 3;
        int ks = (c & 7) ^ (jl & 7);
        aoff[r] = (size_t)(mi*128 + jl) * kstride + ks*8;
        boff[r] = (size_t)(ni*128 + jl) * kstride + ks*8;
    }
    const int wm = w & 1, wn = w >> 1;
    const int q = lane >> 4, lm = lane & 15;
    const int ajl = wm*64 + lm;
    const int aoffl = (ajl*8 + (q ^ (ajl & 7))) * 16;
    const int bjl = wn*64 + lm;
    const int boffl = (bjl*8 + (q ^ (bjl & 7))) * 16;

    const int kq = kiters >> 4;        // kiters multiple of 32 (Kc mult of 2048)
    for (int kt = z*kq; kt < (z+1)*kq; ++kt) {
        __syncthreads();
        const _Float16* gc = C + (size_t)kt * 64;
        const _Float16* gs = S + (size_t)kt * 64;
        #pragma unroll
        for (int r = 0; r < 4; ++r) {
            size_t dst = (size_t)(r*256 + w*64)*16;
            gload16(gc + aoff[r], (char*)ldsCa + dst);
            gload16(gs + aoff[r], (char*)ldsSa + dst);
            gload16(gc + boff[r], (char*)ldsCb + dst);
            gload16(gs + boff[r], (char*)ldsSb + dst);
        }
        __syncthreads();
        #pragma unroll
        for (int ks = 0; ks < 2; ++ks) {
            f16x8 bfC[4], bfS[4];
            #pragma unroll
            for (int nt = 0; nt < 4; ++nt) {
                bfC[nt] = *(const f16x8*)((const char*)ldsCb + ((boffl ^ (ks*64)) + nt*2048));
                bfS[nt] = *(const f16x8*)((const char*)ldsSb + ((boffl ^ (ks*64)) + nt*2048));
            }
            #pragma unroll
            for (int mt = 0; mt < 4; ++mt) {
                f16x8 afC = *(const f16x8*)((const char*)ldsCa + ((aoffl ^ (ks*64)) + mt*2048));
                f16x8 afS = *(const f16x8*)((const char*)ldsSa + ((aoffl ^ (ks*64)) + mt*2048));
                f16x8 nfS;
                #pragma unroll
                for (int e = 0; e < 8; ++e) nfS[e] = -afS[e];
                #pragma unroll
                for (int nt = 0; nt < 4; ++nt) {
                    accR[mt][nt] = __builtin_amdgcn_mfma_f32_16x16x32_f16(afC, bfC[nt], accR[mt][nt], 0, 0, 0);
                    accR[mt][nt] = __builtin_amdgcn_mfma_f32_16x16x32_f16(afS, bfS[nt], accR[mt][nt], 0, 0, 0);
                    accP[mt][nt] = __builtin_amdgcn_mfma_f32_16x16x32_f16(afC, bfS[nt], accP[mt][nt], 0, 0, 0);
                    accP[mt][nt] = __builtin_amdgcn_mfma_f32_16x16x32_f16(nfS, bfC[nt], accP[mt][nt], 0, 0, 0);
                }
            }
        }
    }
    #pragma unroll
    for (int mt = 0; mt < 4; ++mt) {
        #pragma unroll
        for (int nt = 0; nt < 4; ++nt) {
            int row0 = mi*128 + wm*64 + mt*16 + q*4;
            int col  = ni*128 + wn*64 + nt*16 + lm;
            float* rp = R  + (size_t)row0 * BAP + col;
            float* pp = Pm + (size_t)row0 * BAP + col;
            #pragma unroll
            for (int rr = 0; rr < 4; ++rr) {
                atomicAdd(rp + (size_t)rr * BAP, accR[mt][nt][rr]);
                atomicAdd(pp + (size_t)rr * BAP, accP[mt][nt][rr]);
            }
        }
    }
}

// ---------------- xd = DI * Hp^H rd ----------------
__global__ __launch_bounds__(256) void xd_init(const float* __restrict__ ay, const float* __restrict__ ax,
                                               const float* __restrict__ rd, float2* __restrict__ xd) {
    int j = blockIdx.x;
    int t = threadIdx.x;
    __shared__ float redr[256], redi[256];
    if (j >= 2000) { if (t == 0) xd[j] = make_float2(0.f, 0.f); return; }
    int jy = j % 40, jx = j / 40;
    float why = ((float)jy * (200.0f/39.0f) - 100.0f) * 1e-3f;
    float whx = ((float)jx * (200.0f/49.0f) - 100.0f) * 1e-3f;
    float sr = 0.f, si = 0.f;
    for (int i = t; i < KKTOT; i += 256) {
        float fr = phase_frac(ay[i]-why, ax[i]-whx);
        float r = rd[i];
        sr = fmaf(r, __builtin_amdgcn_cosf(fr), sr);
        si = fmaf(r, __builtin_amdgcn_sinf(fr), si);
    }
    redr[t] = sr; redi[t] = si;
    __syncthreads();
    for (int s2 = 128; s2 > 0; s2 >>= 1) {
        if (t < s2) { redr[t] += redr[t+s2]; redi[t] += redi[t+s2]; }
        __syncthreads();
    }
    if (t == 0) xd[j] = make_float2(0.01f * redr[0], -0.01f * redi[0]);
}

// ---------------- build G from upper-tri planes, Hermitian mirror ----------------
__global__ __launch_bounds__(256) void build_G_tile(const float* __restrict__ R, const float* __restrict__ Pm,
                                                    float2* __restrict__ G) {
    int ti = blockIdx.y, tj = blockIdx.x;
    if (tj < ti) return;
    __shared__ float2 tile[64][65];
    int t = threadIdx.x;
    #pragma unroll
    for (int r = 0; r < 16; ++r) {
        int e = t + 256*r;
        int lr = e >> 6, lc = e & 63;
        size_t mn = (size_t)(ti*64 + lr) * BAP + tj*64 + lc;
        float re = 0.01f * R[mn];
        float im = 0.01f * Pm[mn];
        G[mn] = make_float2(re, im);
        tile[lc][lr] = make_float2(re, -im);
    }
    if (tj == ti) return;
    __syncthreads();
    #pragma unroll
    for (int r = 0; r < 16; ++r) {
        int e = t + 256*r;
        int lr = e >> 6, lc = e & 63;
        G[(size_t)(tj*64 + lr) * BAP + ti*64 + lc] = tile[lr][lc];
    }
}

// ---------------- panel factorization, two-level blocked (NB=16 subs) ----------------
// Key: column j of Rcm freezes at its step-j value => Rcm doubles as the t/row history
// (t_j = col_j*dinv_j, row_j = conj(col_j) via Hermitian). Per sub: phase A applies all
// prior steps as a register-accumulated rank-k update to this sub's 16 columns (Rcm & Vcm);
// phase B runs 16 serial steps touching only this sub's columns. V accumulated as in r12.
__global__ __launch_bounds__(256) void panel_factor(const float2* __restrict__ G, const float2* __restrict__ xd,
                                                    float2* __restrict__ Vout, float2* __restrict__ vv,
                                                    float* __restrict__ sarr, int p0) {
    __shared__ float2 Rcm[64*65];   // Rcm[c*65+i] = M[i][c]
    __shared__ float2 Vcm[64*65];   // V-accum; finalized V columns after their step
    __shared__ float2 xdp[64];
    __shared__ float2 dinvv[64];
    int t = threadIdx.x;
    int i = t & 63, cg = t >> 6;
    #pragma unroll
    for (int r = 0; r < 16; ++r) {
        int e = t + 256*r;
        int ci = e & 63, ri = e >> 6;
        Rcm[ci*65 + ri] = G[(size_t)(p0+ri)*BAP + p0 + ci];
    }
    #pragma unroll
    for (int r = 0; r < 17; ++r) {
        int e = t + 256*r;
        if (e < 64*65) Vcm[e] = make_float2(0.f, 0.f);
    }
    if (cg == 0) xdp[i] = xd[p0 + i];
    __syncthreads();

    for (int sub = 0; sub < 4; ++sub) {
        int cS = sub*16 + cg*4;                 // this wave's 4 columns within the sub
        // ---- Phase A: apply all prior steps to this sub's columns (register-accumulated) ----
        float2 raccR[4], raccV[4];
        #pragma unroll
        for (int u = 0; u < 4; ++u) {
            raccR[u] = Rcm[(cS+u)*65 + i];
            raccV[u] = Vcm[(cS+u)*65 + i];
        }
        for (int j = 0; j < sub*16; ++j) {
            float2 dv = dinvv[j];
            float2 colji = Rcm[j*65 + i];       // frozen col_j[i]
            float2 tj = cmulf(colji, dv);
            float2 vji = Vcm[j*65 + i];         // finalized V[i][j]
            #pragma unroll
            for (int u = 0; u < 4; ++u) {
                float2 x = Rcm[j*65 + cS + u];  // frozen col_j[c] (broadcast)
                float2 rv = make_float2(x.x, -x.y);   // row_j(c) = conj(col_j[c])
                raccR[u].x -= tj.x*rv.x - tj.y*rv.y;
                raccR[u].y -= tj.x*rv.y + tj.y*rv.x;
                raccV[u].x += vji.x*rv.x - vji.y*rv.y;
                raccV[u].y += vji.x*rv.y + vji.y*rv.x;
            }
        }
        #pragma unroll
        for (int u = 0; u < 4; ++u) {
            Rcm[(cS+u)*65 + i] = raccR[u];
            Vcm[(cS+u)*65 + i] = raccV[u];
        }
        __syncthreads();
        // ---- Phase B: 16 serial steps within the sub (only sub columns updated) ----
        for (int jj = 0; jj < 16; ++jj) {
            int j = sub*16 + jj;
            // phase 1: reads only
            float2 pr = Rcm[j*65 + j];
            float dr = 1.0f + pr.x, dii = pr.y;
            float idn = 1.0f / (dr*dr + dii*dii);
            float2 dv = make_float2(dr*idn, -dii*idn);
            float2 colv = Rcm[j*65 + i];
            float2 tp = cmulf(colv, dv);
            float2 mv = Vcm[j*65 + i];
            float2 Vij = cmulf(make_float2((i==j ? 1.0f : 0.0f) - mv.x, -mv.y), dv);
            float2 vj = xdp[j];
            float2 rowv[4];
            #pragma unroll
            for (int u = 0; u < 4; ++u) {
                float2 x = Rcm[j*65 + cS + u];
                rowv[u] = make_float2(x.x, -x.y);
            }
            __syncthreads();
            // phase 2: writes
            if (cg == 0) {
                Vcm[j*65 + i] = Vij;            // finalize V column j
                float2 xi = xdp[i];
                xi.x -= tp.x*vj.x - tp.y*vj.y;
                xi.y -= tp.x*vj.y + tp.y*vj.x;
                xdp[i] = xi;
            }
            if (t == j) { dinvv[j] = dv; vv[j] = vj; sarr[j] = dr; }
            #pragma unroll
            for (int u = 0; u < 4; ++u) {
                int c = cS + u;
                if (c > j) {
                    float2 rv = rowv[u];
                    float2 cur = Rcm[c*65 + i];
                    cur.x -= tp.x*rv.x - tp.y*rv.y;
                    cur.y -= tp.x*rv.y + tp.y*rv.x;
                    Rcm[c*65 + i] = cur;
                    float2 m = Vcm[c*65 + i];
                    m.x += Vij.x*rv.x - Vij.y*rv.y;
                    m.y += Vij.x*rv.y + Vij.y*rv.x;
                    Vcm[c*65 + i] = m;
                }
            }
            __syncthreads();
        }
    }
    // export V[k][j] row-major: Vout[k*64+j] = Vcm[j*65+k]
    #pragma unroll
    for (int r = 0; r < 16; ++r) {
        int e = t + 256*r;
        int ri = e >> 6, ci = e & 63;
        Vout[e] = Vcm[ci*65 + ri];
    }
}

// ---------------- panel_T: dense T = src·V (2048x64x64) + xd -= T·v ----------------
__global__ __launch_bounds__(256) void panel_T(const float2* __restrict__ G, float2* __restrict__ xd,
                                               float2* __restrict__ T,
                                               const float2* __restrict__ V, const float2* __restrict__ vv, int p0) {
    __shared__ float srcRe[64][64];
    __shared__ float srcIm[64][64];
    __shared__ float2 Vb[64*64];
    __shared__ float2 vb[64];
    __shared__ float2 xred[4][64];
    int t = threadIdx.x;
    int ri = t & 63, cg = t >> 6;
    int r = blockIdx.x * 64 + ri;
    {
        const float2* gp = G + (size_t)r * BAP + p0 + cg*16;
        #pragma unroll
        for (int k = 0; k < 16; ++k) {
            float2 g = gp[k];
            srcRe[cg*16 + k][ri] = g.x;
            srcIm[cg*16 + k][ri] = g.y;
        }
    }
    #pragma unroll
    for (int q = 0; q < 16; ++q) {
        int e = t + 256*q;
        Vb[e] = V[e];
    }
    if (cg == 0) vb[ri] = vv[ri];
    __syncthreads();
    int jb = cg * 16;
    float2 acc[16];
    #pragma unroll
    for (int jj = 0; jj < 16; ++jj) acc[jj] = make_float2(0.f, 0.f);
    for (int k = 0; k < 64; ++k) {
        float sx = srcRe[k][ri];
        float sy = srcIm[k][ri];
        #pragma unroll
        for (int jj = 0; jj < 16; ++jj) {
            float2 vk = Vb[k*64 + jb + jj];
            acc[jj].x = fmaf(sx, vk.x, fmaf(-sy, vk.y, acc[jj].x));
            acc[jj].y = fmaf(sx, vk.y, fmaf( sy, vk.x, acc[jj].y));
        }
    }
    float2 xp = make_float2(0.f, 0.f);
    #pragma unroll
    for (int jj = 0; jj < 16; ++jj) {
        T[(size_t)(jb + jj) * BAP + r] = acc[jj];
        float2 vj = vb[jb + jj];
        xp.x += acc[jj].x*vj.x - acc[jj].y*vj.y;
        xp.y += acc[jj].x*vj.y + acc[jj].y*vj.x;
    }
    xred[cg][ri] = xp;
    __syncthreads();
    if (cg == 0) {
        float2 x = xd[r];
        #pragma unroll
        for (int g = 0; g < 4; ++g) { x.x -= xred[g][ri].x; x.y -= xred[g][ri].y; }
        xd[r] = x;
    }
}

// ---------------- trailing update (future cols) + fused diag fix (past diags) ----------------
// W[k][c] = s[k]*conj(T[k][c]).  Last blockIdx.x row does diag duty:
// G[j][j].x -= sum_k s_k |T[k][j]|^2 for j < jmax (disjoint writes from column tiles).
__global__ __launch_bounds__(256) void trailing_update(float2* __restrict__ G,
                                                       const float2* __restrict__ T, const float* __restrict__ s,
                                                       int coff, int jmax) {
    if (blockIdx.x == gridDim.x - 1) {
        int j = blockIdx.y * 128 + (threadIdx.x & 127);
        if (threadIdx.x < 128 && j < jmax) {
            float acc = 0.f;
            for (int k = 0; k < 64; ++k) {
                float2 tv = T[(size_t)k * BAP + j];
                acc = fmaf(s[k], fmaf(tv.x, tv.x, tv.y*tv.y), acc);
            }
            size_t jj2 = (size_t)j * BAP + j;
            float2 g = G[jj2];
            g.x -= acc;
            G[jj2] = g;
        }
        return;
    }
    __shared__ float2 Tb[16][128];
    __shared__ float2 Wb[16][64];
    int t = threadIdx.x;
    int cx = (blockIdx.x + coff) * 64, ry = blockIdx.y * 128;
    int rq = t >> 4, cq = t & 15;
    float2 acc[8][4];
    #pragma unroll
    for (int si = 0; si < 8; ++si)
        #pragma unroll
        for (int u = 0; u < 4; ++u) acc[si][u] = make_float2(0.f, 0.f);

    for (int k0 = 0; k0 < 64; k0 += 16) {
        __syncthreads();
        #pragma unroll
        for (int r = 0; r < 4; ++r) {
            int e = t + 256*r;
            int k = e >> 6, x4 = e & 63;
            *(float4*)&Tb[k][x4*2] = *(const float4*)(T + (size_t)(k0+k) * BAP + ry + x4*2);
        }
        #pragma unroll
        for (int r = 0; r < 2; ++r) {
            int e = t + 256*r;
            int k = e >> 5, x4 = e & 31;
            float sk = s[k0+k];
            float4 tv = *(const float4*)(T + (size_t)(k0+k) * BAP + cx + x4*2);
            Wb[k][x4*2]   = make_float2(tv.x*sk, -tv.y*sk);
            Wb[k][x4*2+1] = make_float2(tv.z*sk, -tv.w*sk);
        }
        __syncthreads();
        #pragma unroll
        for (int k = 0; k < 16; ++k) {
            float2 av[8], bv[4];
            #pragma unroll
            for (int si = 0; si < 8; ++si) av[si] = Tb[k][rq + 16*si];
            #pragma unroll
            for (int u = 0; u < 4; ++u) bv[u] = Wb[k][cq + 16*u];
            #pragma unroll
            for (int si = 0; si < 8; ++si)
                #pragma unroll
                for (int u = 0; u < 4; ++u) {
                    acc[si][u].x = fmaf(av[si].x, bv[u].x, fmaf(-av[si].y, bv[u].y, acc[si][u].x));
                    acc[si][u].y = fmaf(av[si].x, bv[u].y, fmaf( av[si].y, bv[u].x, acc[si][u].y));
                }
        }
    }
    #pragma unroll
    for (int si = 0; si < 8; ++si) {
        float2* gp = G + (size_t)(ry + rq + 16*si) * BAP + cx + cq;
        #pragma unroll
        for (int u = 0; u < 4; ++u) {
            float2 gg = gp[16*u];
            gg.x -= acc[si][u].x;
            gg.y -= acc[si][u].y;
            gp[16*u] = gg;
        }
    }
}

// ---------------- finalize ----------------
__global__ __launch_bounds__(256) void finalize_k(const float2* __restrict__ G, const float2* __restrict__ xd,
                                                  float* __restrict__ out, int out_size) {
    int o = blockIdx.x * 256 + threadIdx.x;
    if (o >= 2000) return;
    int b = o / 50, a = o % 50;
    int j = b * 50 + (49 - a);
    float2 x = xd[j];
    float2 g = G[(size_t)j * BAP + j];
    float den = 1.0f / (g.x*g.x + g.y*g.y);
    float re = (x.x*g.x + x.y*g.y) * den;
    float im = (x.y*g.x - x.x*g.y) * den;
    out[o] = re;
    if (out_size >= 4000) out[2000 + o] = im;
}

extern "C" void kernel_launch(void* const* d_in, const int* in_sizes, int n_in,
                              void* d_out, int out_size, void* d_ws, size_t ws_size,
                              hipStream_t stream) {
    const float* sar = (const float*)d_in[0];
    const int*   py  = (const int*)d_in[1];
    float* out = (float*)d_out;
    char* w = (char*)d_ws;
    size_t off = 0;
    auto take = [&](size_t sz) -> char* { char* p = w + off; off += (sz + 255) & ~(size_t)255; return p; };

    float*  R   = (float*)take((size_t)BAP*BAP*4);
    float*  Pm  = (float*)take((size_t)BAP*BAP*4);
    float2* G  = (float2*)take((size_t)BAP*BAP*8);
    float2* T  = (float2*)take((size_t)64*BAP*8);
    float2* xd = (float2*)take((size_t)BAP*8);
    float*  ay = (float*)take((size_t)KPADMAX*4);
    float*  ax = (float*)take((size_t)KPADMAX*4);
    float*  rd = (float*)take((size_t)KPADMAX*4);
    float2* Vp = (float2*)take(64*64*8);
    float2* vv   = (float2*)take(64*8);
    float*  sarr = (float*)take(64*4);

    size_t avail = (ws_size > off + 4096) ? (ws_size - off - 4096) : 0;
    long long Kc = (long long)(avail / 8192) & ~2047LL;
    if (Kc > KPADMAX) Kc = KPADMAX;
    if (Kc < 2048) Kc = 2048;
    int nch = (int)((KKTOT + Kc - 1) / Kc);
    long long Kc2 = 2048LL * ((KKTOT + (long long)nch*2048 - 1) / ((long long)nch*2048));
    if (Kc2 >= 2048 && Kc2 <= Kc) Kc = Kc2;
    _Float16* C = (_Float16*)take((size_t)BAP * Kc * 2);
    _Float16* S = (_Float16*)take((size_t)BAP * Kc * 2);
    int kiters = (int)(Kc / 64);

    hipMemsetAsync(R, 0, (size_t)BAP*BAP*4*2, stream);  // R, Pm contiguous

    decode_k<<<dim3(391), dim3(256), 0, stream>>>(sar, py, ay, ax, rd);
    xd_init<<<dim3(BAP), dim3(256), 0, stream>>>(ay, ax, rd, xd);

    for (int c0 = 0; c0 < nch; ++c0) {
        gen_cs<<<dim3((unsigned)(Kc/2048), BAP), dim3(256), 0, stream>>>(C, S, ay, ax, (int)(c0*Kc), (int)Kc);
        gemm_ut<<<dim3(136, 16), dim3(256), 0, stream>>>(C, S, R, Pm, kiters, (int)Kc);
    }
    build_G_tile<<<dim3(32, 32), dim3(256), 0, stream>>>(R, Pm, G);

    for (int p = 0; p < 32; ++p) {
        int p0 = p * 64;
        panel_factor<<<dim3(1), dim3(256), 0, stream>>>(G, xd, Vp, vv, sarr, p0);
        panel_T<<<dim3(32), dim3(256), 0, stream>>>(G, xd, T, Vp, vv, p0);
        trailing_update<<<dim3(32 - p, 16), dim3(256), 0, stream>>>(G, T, sarr, p + 1, p0 + 64);
    }
    finalize_k<<<dim3(8), dim3(256), 0, stream>>>(G, xd, out, out_size);
}